// Round 3
// baseline (1636.033 us; speedup 1.0000x reference)
//
#include <hip/hip_runtime.h>
#include <hip/hip_bf16.h>

// Problem constants: T=512 tokens, D=2048 hidden, E=64 experts, K=8 top-k, F=768.
#define T_TOK 512
#define D_DIM 2048
#define E_NUM 64
#define K_TOP 8
#define F_DIM 768

typedef __bf16 bf16x8 __attribute__((ext_vector_type(8)));
typedef float  f32x4  __attribute__((ext_vector_type(4)));

// ---------------- workspace layout (bytes) ----------------
// cnt    : int[64]            @ 0
// ids    : int[64*512]        @ 4096
// pair_w : float[4096]        @ 139264
// H      : bf16[4096*768]     @ 262144
// Y      : bf16[4096*2048]    @ 8388608
#define WS_IDS   4096
#define WS_PW    139264
#define WS_H     262144
#define WS_Y     8388608

__global__ void zero_cnt_kernel(int* __restrict__ cnt) {
    if (threadIdx.x < E_NUM) cnt[threadIdx.x] = 0;
}

// ---------------- router: logits -> softmax -> top-8 -> renorm ----------------
__global__ __launch_bounds__(256) void router_kernel(
        const float* __restrict__ x, const float* __restrict__ gw,
        float* __restrict__ pair_w, int* __restrict__ cnt, int* __restrict__ ids) {
    const int t   = blockIdx.x;
    const int tid = threadIdx.x;
    const int e   = tid & 63;
    const int c   = tid >> 6;
    const float* xr = x + (size_t)t * D_DIM;
    const int k0 = c * (D_DIM / 4);
    float s = 0.f;
    #pragma unroll 8
    for (int k = 0; k < D_DIM / 4; k++) {
        s += xr[k0 + k] * gw[(size_t)(k0 + k) * E_NUM + e];
    }
    __shared__ float part[4][64];
    part[c][e] = s;
    __syncthreads();
    if (tid < 64) {  // first wave only; lane == e
        float logit = part[0][e] + part[1][e] + part[2][e] + part[3][e];
        float cur = logit;
        float selV[8]; int selE[8];
        #pragma unroll
        for (int i = 0; i < 8; i++) {
            float bv = cur; int bi = e;
            #pragma unroll
            for (int off = 32; off > 0; off >>= 1) {
                float ov = __shfl_xor(bv, off);
                int   oi = __shfl_xor(bi, off);
                if (ov > bv || (ov == bv && oi < bi)) { bv = ov; bi = oi; }
            }
            selV[i] = bv; selE[i] = bi;
            if (e == bi) cur = -INFINITY;
        }
        const float m = selV[0];
        float sum = 0.f;
        #pragma unroll
        for (int i = 0; i < 8; i++) sum += __expf(selV[i] - m);
        float myW = 0.f; int myE = 0;
        #pragma unroll
        for (int i = 0; i < 8; i++) {
            if (e == i) { myW = __expf(selV[i] - m) / sum; myE = selE[i]; }
        }
        if (e < 8) {
            pair_w[t * K_TOP + e] = myW;
            int pos = atomicAdd(&cnt[myE], 1);
            ids[myE * T_TOK + pos] = t * K_TOP + e;  // token = id>>3
        }
    }
}

// ================= mlp1: H[pair] = silu(X@Wg) * (X@Wu) =================
// Barrier-free, LDS-free, explicit 2-deep software pipeline with NAMED
// register sets (static indexing only — runtime-indexed arrays go to
// scratch). While step k's set is consumed (s_waitcnt on its loads), step
// k+1's ~24 loads stay outstanding -> counted vmcnt, latency hidden.
__device__ __forceinline__ void mlp1_load_b(
        const float* __restrict__ bg, const float* __restrict__ bu, int ks,
        float (&gv)[8], float (&uv)[8]) {
    #pragma unroll
    for (int i = 0; i < 8; i++) {
        const int off = (ks * 32 + i) * F_DIM;
        gv[i] = bg[off];
        uv[i] = bu[off];
    }
}

__device__ __forceinline__ void mlp1_load_a(
        const float4* const (&ar)[4], int ks, float4 (&a0)[4], float4 (&a1)[4]) {
    #pragma unroll
    for (int m = 0; m < 4; m++) {
        a0[m] = ar[m][ks * 8];
        a1[m] = ar[m][ks * 8 + 1];
    }
}

__device__ __forceinline__ void mlp1_step(
        const float (&gv)[8], const float (&uv)[8],
        const float4 (&a0)[4], const float4 (&a1)[4],
        f32x4 (&accg)[4], f32x4 (&accu)[4]) {
    bf16x8 bgf, buf8;
    #pragma unroll
    for (int i = 0; i < 8; i++) { bgf[i] = (__bf16)gv[i]; buf8[i] = (__bf16)uv[i]; }
    #pragma unroll
    for (int m = 0; m < 4; m++) {
        bf16x8 af;
        af[0]=(__bf16)a0[m].x; af[1]=(__bf16)a0[m].y;
        af[2]=(__bf16)a0[m].z; af[3]=(__bf16)a0[m].w;
        af[4]=(__bf16)a1[m].x; af[5]=(__bf16)a1[m].y;
        af[6]=(__bf16)a1[m].z; af[7]=(__bf16)a1[m].w;
        accg[m] = __builtin_amdgcn_mfma_f32_16x16x32_bf16(af, bgf,  accg[m], 0, 0, 0);
        accu[m] = __builtin_amdgcn_mfma_f32_16x16x32_bf16(af, buf8, accu[m], 0, 0, 0);
    }
}

__global__ __launch_bounds__(256, 3) void mlp1_kernel(
        const float* __restrict__ x,
        const float* __restrict__ w_gate, const float* __restrict__ w_up,
        const int* __restrict__ cnt, const int* __restrict__ ids,
        __bf16* __restrict__ H) {
    const int e     = blockIdx.z;
    const int mtile = blockIdx.y;
    const int ftile = blockIdx.x;   // 12 tiles of 64
    const int n = cnt[e];
    if (mtile * 64 >= n) return;

    const int tid  = threadIdx.x;
    const int lane = tid & 63;
    const int w    = tid >> 6;
    const int g16  = lane >> 4;     // 0..3
    const int l16  = lane & 15;

    // A row pointers, pre-offset by k0 = 8*g16 floats (float4 granularity)
    const float4* ar[4];
    #pragma unroll
    for (int m = 0; m < 4; m++) {
        const int p   = mtile * 64 + m * 16 + l16;
        const int tok = (p < n) ? (ids[e * T_TOK + p] >> 3) : 0;
        ar[m] = (const float4*)(x + (size_t)tok * D_DIM) + g16 * 2;
    }
    const int fcol = ftile * 64 + w * 16 + l16;
    const size_t bbase = (size_t)e * D_DIM * F_DIM + (size_t)(g16 * 8) * F_DIM + fcol;
    const float* bg = w_gate + bbase;
    const float* bu = w_up   + bbase;

    f32x4 accg[4], accu[4];
    #pragma unroll
    for (int m = 0; m < 4; m++) {
        accg[m][0]=0.f; accg[m][1]=0.f; accg[m][2]=0.f; accg[m][3]=0.f;
        accu[m][0]=0.f; accu[m][1]=0.f; accu[m][2]=0.f; accu[m][3]=0.f;
    }

    // pipeline registers (two named sets — no runtime indexing)
    float  gvA[8], uvA[8], gvB[8], uvB[8];
    float4 a0A[4], a1A[4], a0B[4], a1B[4];

    mlp1_load_b(bg, bu, 0, gvA, uvA);
    mlp1_load_a(ar, 0, a0A, a1A);
    mlp1_load_b(bg, bu, 1, gvB, uvB);
    mlp1_load_a(ar, 1, a0B, a1B);

    const int NK = D_DIM / 32;  // 64
    for (int ks = 0; ks < NK; ks += 2) {
        // prefetch ks+2 into set A while set B is in flight
        mlp1_step(gvA, uvA, a0A, a1A, accg, accu);
        const int kp0 = (ks + 2 < NK) ? ks + 2 : 0;  // clamped dummy prefetch at tail
        mlp1_load_b(bg, bu, kp0, gvA, uvA);
        mlp1_load_a(ar, kp0, a0A, a1A);
        // prefetch ks+3 into set B while set A is in flight
        mlp1_step(gvB, uvB, a0B, a1B, accg, accu);
        const int kp1 = (ks + 3 < NK) ? ks + 3 : 0;
        mlp1_load_b(bg, bu, kp1, gvB, uvB);
        mlp1_load_a(ar, kp1, a0B, a1B);
    }

    // epilogue: h = silu(g)*u -> H[rid][fcol]
    #pragma unroll
    for (int m = 0; m < 4; m++) {
        #pragma unroll
        for (int r = 0; r < 4; r++) {
            const int p = mtile * 64 + m * 16 + g16 * 4 + r;
            if (p < n) {
                const int rid = ids[e * T_TOK + p];
                const float g = accg[m][r], u = accu[m][r];
                const float h = (g / (1.f + __expf(-g))) * u;
                H[(size_t)rid * F_DIM + fcol] = (__bf16)h;
            }
        }
    }
}

// ================= mlp2: Y[pair] = H @ Wd =================
__device__ __forceinline__ void mlp2_load_b(
        const float* __restrict__ bd, int ks, float (&dv)[8]) {
    #pragma unroll
    for (int i = 0; i < 8; i++) dv[i] = bd[(ks * 32 + i) * D_DIM];
}

__device__ __forceinline__ void mlp2_load_a(
        const uint4* const (&hr)[4], int ks, uint4 (&av)[4]) {
    #pragma unroll
    for (int m = 0; m < 4; m++) av[m] = hr[m][ks * 4];
}

__device__ __forceinline__ void mlp2_step(
        const float (&dv)[8], const uint4 (&av)[4], f32x4 (&acc)[4]) {
    bf16x8 bdf;
    #pragma unroll
    for (int i = 0; i < 8; i++) bdf[i] = (__bf16)dv[i];
    #pragma unroll
    for (int m = 0; m < 4; m++) {
        acc[m] = __builtin_amdgcn_mfma_f32_16x16x32_bf16(
            __builtin_bit_cast(bf16x8, av[m]), bdf, acc[m], 0, 0, 0);
    }
}

__global__ __launch_bounds__(256, 4) void mlp2_kernel(
        const __bf16* __restrict__ H, const float* __restrict__ w_down,
        const int* __restrict__ cnt, const int* __restrict__ ids,
        __bf16* __restrict__ Y) {
    const int e     = blockIdx.z;
    const int mtile = blockIdx.y;
    const int dtile = blockIdx.x;   // 32 tiles of 64
    const int n = cnt[e];
    if (mtile * 64 >= n) return;

    const int tid  = threadIdx.x;
    const int lane = tid & 63;
    const int w    = tid >> 6;
    const int g16  = lane >> 4;
    const int l16  = lane & 15;

    const uint4* hr[4];
    #pragma unroll
    for (int m = 0; m < 4; m++) {
        const int p   = mtile * 64 + m * 16 + l16;
        const int rid = (p < n) ? ids[e * T_TOK + p] : 0;
        hr[m] = (const uint4*)(H + (size_t)rid * F_DIM) + g16;  // k0 = 8*g16
    }
    const int dcol = dtile * 64 + w * 16 + l16;
    const float* bd = w_down + (size_t)e * F_DIM * D_DIM + (size_t)(g16 * 8) * D_DIM + dcol;

    f32x4 acc[4];
    #pragma unroll
    for (int m = 0; m < 4; m++) { acc[m][0]=0.f; acc[m][1]=0.f; acc[m][2]=0.f; acc[m][3]=0.f; }

    float dvA[8], dvB[8];
    uint4 avA[4], avB[4];
    mlp2_load_b(bd, 0, dvA);
    mlp2_load_a(hr, 0, avA);
    mlp2_load_b(bd, 1, dvB);
    mlp2_load_a(hr, 1, avB);

    const int NK = F_DIM / 32;  // 24
    for (int ks = 0; ks < NK; ks += 2) {
        mlp2_step(dvA, avA, acc);
        const int kp0 = (ks + 2 < NK) ? ks + 2 : 0;
        mlp2_load_b(bd, kp0, dvA);
        mlp2_load_a(hr, kp0, avA);
        mlp2_step(dvB, avB, acc);
        const int kp1 = (ks + 3 < NK) ? ks + 3 : 0;
        mlp2_load_b(bd, kp1, dvB);
        mlp2_load_a(hr, kp1, avB);
    }

    #pragma unroll
    for (int m = 0; m < 4; m++) {
        #pragma unroll
        for (int r = 0; r < 4; r++) {
            const int p = mtile * 64 + m * 16 + g16 * 4 + r;
            if (p < n) {
                const int rid = ids[e * T_TOK + p];
                Y[(size_t)rid * D_DIM + dcol] = (__bf16)acc[m][r];
            }
        }
    }
}

// ---------------- combine: out[t] = sum_k w[t,k] * Y[t*8+k] ----------------
__global__ __launch_bounds__(256) void combine_kernel(
        const __bf16* __restrict__ Y, const float* __restrict__ pw,
        float* __restrict__ out) {
    const int t   = blockIdx.x;
    const int tid = threadIdx.x;
    const int d0  = tid * 8;
    float acc[8];
    #pragma unroll
    for (int j = 0; j < 8; j++) acc[j] = 0.f;
    #pragma unroll
    for (int k = 0; k < K_TOP; k++) {
        const float wgt = pw[t * K_TOP + k];
        bf16x8 v = *(const bf16x8*)(Y + (size_t)(t * K_TOP + k) * D_DIM + d0);
        #pragma unroll
        for (int j = 0; j < 8; j++) acc[j] += wgt * (float)v[j];
    }
    #pragma unroll
    for (int j = 0; j < 8; j++) out[(size_t)t * D_DIM + d0 + j] = acc[j];
}

extern "C" void kernel_launch(void* const* d_in, const int* in_sizes, int n_in,
                              void* d_out, int out_size, void* d_ws, size_t ws_size,
                              hipStream_t stream) {
    const float* x      = (const float*)d_in[0];
    const float* gw     = (const float*)d_in[1];
    const float* w_gate = (const float*)d_in[2];
    const float* w_up   = (const float*)d_in[3];
    const float* w_down = (const float*)d_in[4];
    float* out = (float*)d_out;

    char* ws = (char*)d_ws;
    int*    cnt = (int*)(ws);
    int*    ids = (int*)(ws + WS_IDS);
    float*  pw  = (float*)(ws + WS_PW);
    __bf16* H   = (__bf16*)(ws + WS_H);
    __bf16* Y   = (__bf16*)(ws + WS_Y);

    zero_cnt_kernel<<<1, 64, 0, stream>>>(cnt);
    router_kernel<<<T_TOK, 256, 0, stream>>>(x, gw, pw, cnt, ids);
    // y-dim 8 covers any routing skew (n_e <= 512); empty tiles exit on cnt read.
    mlp1_kernel<<<dim3(F_DIM / 64, 8, E_NUM), 256, 0, stream>>>(x, w_gate, w_up, cnt, ids, H);
    mlp2_kernel<<<dim3(D_DIM / 64, 8, E_NUM), 256, 0, stream>>>(H, w_down, cnt, ids, Y);
    combine_kernel<<<T_TOK, 256, 0, stream>>>(Y, pw, out);
}

// Round 4
// 609.610 us; speedup vs baseline: 2.6837x; 2.6837x over previous
//
#include <hip/hip_runtime.h>
#include <hip/hip_bf16.h>

// Problem constants: T=512 tokens, D=2048 hidden, E=64 experts, K=8 top-k, F=768.
#define T_TOK 512
#define D_DIM 2048
#define E_NUM 64
#define K_TOP 8
#define F_DIM 768

typedef __bf16 bf16x8 __attribute__((ext_vector_type(8)));
typedef float  f32x4  __attribute__((ext_vector_type(4)));

#define AS1 __attribute__((address_space(1)))
#define AS3 __attribute__((address_space(3)))

// async global->LDS, 16B per lane; LDS dest is wave-uniform base + lane*16.
__device__ __forceinline__ void gll16(const void* g, void* l) {
    __builtin_amdgcn_global_load_lds((const AS1 uint32_t*)g, (AS3 uint32_t*)l, 16, 0, 0);
}

// ---------------- workspace layout (bytes) ----------------
// cnt  : int[64]          @ 0
// ids  : int[64*512]      @ 4096
// pw   : float[4096]      @ 139264
// Xbf  : bf16[512*2048]   @ 155648   (2 MB)
// H    : bf16[4096*768]   @ 2252800  (6 MB)
// Y    : bf16[4096*2048]  @ 8544256  (16 MB)   total ~24.2 MB
#define WS_IDS   4096
#define WS_PW    139264
#define WS_XBF   155648
#define WS_H     2252800
#define WS_Y     8544256

__global__ void zero_cnt_kernel(int* __restrict__ cnt) {
    if (threadIdx.x < E_NUM) cnt[threadIdx.x] = 0;
}

// X fp32 -> bf16 pre-pass (2 MB write; makes MFMA A-frags direct uint4 loads)
__global__ __launch_bounds__(256) void xcvt_kernel(
        const float* __restrict__ x, __bf16* __restrict__ xb) {
    const size_t i = ((size_t)blockIdx.x * 256 + threadIdx.x) * 8;
    const float4 a = *(const float4*)(x + i);
    const float4 b = *(const float4*)(x + i + 4);
    bf16x8 v;
    v[0]=(__bf16)a.x; v[1]=(__bf16)a.y; v[2]=(__bf16)a.z; v[3]=(__bf16)a.w;
    v[4]=(__bf16)b.x; v[5]=(__bf16)b.y; v[6]=(__bf16)b.z; v[7]=(__bf16)b.w;
    *(uint4*)(xb + i) = __builtin_bit_cast(uint4, v);
}

// ---------------- router: logits -> softmax -> top-8 -> renorm ----------------
__global__ __launch_bounds__(256) void router_kernel(
        const float* __restrict__ x, const float* __restrict__ gw,
        float* __restrict__ pair_w, int* __restrict__ cnt, int* __restrict__ ids) {
    const int t   = blockIdx.x;
    const int tid = threadIdx.x;
    const int e   = tid & 63;
    const int c   = tid >> 6;
    const float* xr = x + (size_t)t * D_DIM;
    const int k0 = c * (D_DIM / 4);
    float s = 0.f;
    #pragma unroll 8
    for (int k = 0; k < D_DIM / 4; k++) {
        s += xr[k0 + k] * gw[(size_t)(k0 + k) * E_NUM + e];
    }
    __shared__ float part[4][64];
    part[c][e] = s;
    __syncthreads();
    if (tid < 64) {  // first wave only; lane == e
        float logit = part[0][e] + part[1][e] + part[2][e] + part[3][e];
        float cur = logit;
        float selV[8]; int selE[8];
        #pragma unroll
        for (int i = 0; i < 8; i++) {
            float bv = cur; int bi = e;
            #pragma unroll
            for (int off = 32; off > 0; off >>= 1) {
                float ov = __shfl_xor(bv, off);
                int   oi = __shfl_xor(bi, off);
                if (ov > bv || (ov == bv && oi < bi)) { bv = ov; bi = oi; }
            }
            selV[i] = bv; selE[i] = bi;
            if (e == bi) cur = -INFINITY;
        }
        const float m = selV[0];
        float sum = 0.f;
        #pragma unroll
        for (int i = 0; i < 8; i++) sum += __expf(selV[i] - m);
        float myW = 0.f; int myE = 0;
        #pragma unroll
        for (int i = 0; i < 8; i++) {
            if (e == i) { myW = __expf(selV[i] - m) / sum; myE = selE[i]; }
        }
        if (e < 8) {
            pair_w[t * K_TOP + e] = myW;
            int pos = atomicAdd(&cnt[myE], 1);
            ids[myE * T_TOK + pos] = t * K_TOP + e;  // token = id>>3
        }
    }
}

// ================= mlp1: H[pair] = silu(X@Wg) * (X@Wu) =================
// BM=64 (full expert), BN=64, BK=32. B (gate+up) staged fp32 via
// global_load_lds into double-buffered LDS; manual counted vmcnt(8) +
// raw s_barrier (T3/T4): per k-step 4 gll + 4 A-loads stay in flight
// across barriers. A = pre-converted bf16 X rows, direct uint4 loads.
__global__ __launch_bounds__(256, 3) void mlp1_kernel(
        const __bf16* __restrict__ xb,
        const float* __restrict__ w_gate, const float* __restrict__ w_up,
        const int* __restrict__ cnt, const int* __restrict__ ids,
        __bf16* __restrict__ H) {
    const int e     = blockIdx.z;
    const int mtile = blockIdx.y;
    const int ftile = blockIdx.x;   // 12 tiles of 64
    const int n = cnt[e];
    if (mtile * 64 >= n) return;

    const int tid  = threadIdx.x;
    const int lane = tid & 63;
    const int w    = tid >> 6;
    const int g16  = lane >> 4;
    const int l16  = lane & 15;

    __shared__ __align__(16) float ldsB[8192];  // [buf2][mat2][32k][64col] = 32 KB

    // A row pointers (bf16), frag m: row = mtile*64+m*16+l16, k-chunk g16
    const __bf16* arow[4];
    #pragma unroll
    for (int m = 0; m < 4; m++) {
        const int p   = mtile * 64 + m * 16 + l16;
        const int tok = (p < n) ? (ids[e * T_TOK + p] >> 3) : 0;
        arow[m] = xb + (size_t)tok * D_DIM + g16 * 8;
    }

    // B stage addressing: load j covers k = j*16 + (tid>>4), colgrp = tid&15
    const int colg  = (tid & 15) * 4;
    const int krow0 = tid >> 4;
    const float* bg0 = w_gate + (size_t)e * D_DIM * F_DIM + (size_t)krow0 * F_DIM + ftile * 64 + colg;
    const float* bu0 = w_up   + (size_t)e * D_DIM * F_DIM + (size_t)krow0 * F_DIM + ftile * 64 + colg;
    const int ldsWaveByte = w * 64 * 16;   // wave-uniform LDS base offset

    f32x4 accg[4], accu[4];
    #pragma unroll
    for (int m = 0; m < 4; m++) {
        accg[m][0]=0.f; accg[m][1]=0.f; accg[m][2]=0.f; accg[m][3]=0.f;
        accu[m][0]=0.f; accu[m][1]=0.f; accu[m][2]=0.f; accu[m][3]=0.f;
    }

    uint4 aS0[4], aS1[4];

    auto stage = [&](int buf, int ks) {  // 4 gll per thread
        char* Bg = (char*)(ldsB + buf * 4096);
        char* Bu = (char*)(ldsB + buf * 4096 + 2048);
        const size_t ko = (size_t)ks * 32 * F_DIM;
        #pragma unroll
        for (int j = 0; j < 2; j++) {
            gll16(bg0 + ko + (size_t)j * 16 * F_DIM, Bg + j * 4096 + ldsWaveByte);
            gll16(bu0 + ko + (size_t)j * 16 * F_DIM, Bu + j * 4096 + ldsWaveByte);
        }
    };
    auto aload = [&](uint4 (&as)[4], int ks) {  // 4 vm loads per thread
        #pragma unroll
        for (int m = 0; m < 4; m++) as[m] = *(const uint4*)(arow[m] + ks * 32);
    };
    const int ci = w * 16 + l16;
    auto consume = [&](int buf, uint4 (&as)[4]) {
        const float* Bg = ldsB + buf * 4096;
        const float* Bu = Bg + 2048;
        bf16x8 bgf, buf8;
        #pragma unroll
        for (int i = 0; i < 8; i++) {
            bgf[i]  = (__bf16)Bg[(8 * g16 + i) * 64 + ci];
            buf8[i] = (__bf16)Bu[(8 * g16 + i) * 64 + ci];
        }
        #pragma unroll
        for (int m = 0; m < 4; m++) {
            accg[m] = __builtin_amdgcn_mfma_f32_16x16x32_bf16(
                __builtin_bit_cast(bf16x8, as[m]), bgf,  accg[m], 0, 0, 0);
            accu[m] = __builtin_amdgcn_mfma_f32_16x16x32_bf16(
                __builtin_bit_cast(bf16x8, as[m]), buf8, accu[m], 0, 0, 0);
        }
    };

    // prologue: stage-then-aload, consistent group order (8 vm-ops per group)
    stage(0, 0); aload(aS0, 0);
    stage(1, 1); aload(aS1, 1);

    const int NK = D_DIM / 32;  // 64
    for (int ks = 0; ks + 2 < NK; ks += 2) {
        // even sub-iter: buf0 / aS0
        asm volatile("s_waitcnt vmcnt(8)" ::: "memory");  // group(ks) landed
        __builtin_amdgcn_s_barrier();
        __builtin_amdgcn_sched_barrier(0);
        consume(0, aS0);
        asm volatile("s_waitcnt lgkmcnt(0)" ::: "memory");
        __builtin_amdgcn_sched_barrier(0);
        __builtin_amdgcn_s_barrier();                      // buf0 free to overwrite
        stage(0, ks + 2); aload(aS0, ks + 2);
        // odd sub-iter: buf1 / aS1
        asm volatile("s_waitcnt vmcnt(8)" ::: "memory");  // group(ks+1) landed
        __builtin_amdgcn_s_barrier();
        __builtin_amdgcn_sched_barrier(0);
        consume(1, aS1);
        asm volatile("s_waitcnt lgkmcnt(0)" ::: "memory");
        __builtin_amdgcn_sched_barrier(0);
        __builtin_amdgcn_s_barrier();
        stage(1, ks + 3); aload(aS1, ks + 3);
    }
    // tail pair (no prefetch)
    asm volatile("s_waitcnt vmcnt(8)" ::: "memory");
    __builtin_amdgcn_s_barrier();
    __builtin_amdgcn_sched_barrier(0);
    consume(0, aS0);
    asm volatile("s_waitcnt vmcnt(0)" ::: "memory");
    __builtin_amdgcn_s_barrier();
    __builtin_amdgcn_sched_barrier(0);
    consume(1, aS1);

    // epilogue: h = silu(g)*u -> H[rid][fcol]
    const int fcol = ftile * 64 + ci;
    #pragma unroll
    for (int m = 0; m < 4; m++) {
        #pragma unroll
        for (int r = 0; r < 4; r++) {
            const int p = mtile * 64 + m * 16 + g16 * 4 + r;
            if (p < n) {
                const int rid = ids[e * T_TOK + p];
                const float g = accg[m][r], u = accu[m][r];
                const float h = (g / (1.f + __expf(-g))) * u;
                H[(size_t)rid * F_DIM + fcol] = (__bf16)h;
            }
        }
    }
}

// ================= mlp2: Y[pair] = H @ Wd =================
// Same structure; A = H rows (bf16), B = w_down tile; 2 gll + 4 A = vmcnt(6).
__global__ __launch_bounds__(256, 4) void mlp2_kernel(
        const __bf16* __restrict__ H, const float* __restrict__ w_down,
        const int* __restrict__ cnt, const int* __restrict__ ids,
        __bf16* __restrict__ Y) {
    const int e     = blockIdx.z;
    const int mtile = blockIdx.y;
    const int dtile = blockIdx.x;   // 32 tiles of 64
    const int n = cnt[e];
    if (mtile * 64 >= n) return;

    const int tid  = threadIdx.x;
    const int lane = tid & 63;
    const int w    = tid >> 6;
    const int g16  = lane >> 4;
    const int l16  = lane & 15;

    __shared__ __align__(16) float ldsB[4096];  // [buf2][32k][64col] = 16 KB

    const __bf16* arow[4];
    #pragma unroll
    for (int m = 0; m < 4; m++) {
        const int p   = mtile * 64 + m * 16 + l16;
        const int rid = (p < n) ? ids[e * T_TOK + p] : 0;
        arow[m] = H + (size_t)rid * F_DIM + g16 * 8;
    }

    const int colg  = (tid & 15) * 4;
    const int krow0 = tid >> 4;
    const float* bd0 = w_down + (size_t)e * F_DIM * D_DIM + (size_t)krow0 * D_DIM + dtile * 64 + colg;
    const int ldsWaveByte = w * 64 * 16;

    f32x4 acc[4];
    #pragma unroll
    for (int m = 0; m < 4; m++) { acc[m][0]=0.f; acc[m][1]=0.f; acc[m][2]=0.f; acc[m][3]=0.f; }

    uint4 aS0[4], aS1[4];

    auto stage = [&](int buf, int ks) {  // 2 gll per thread
        char* Bd = (char*)(ldsB + buf * 2048);
        const size_t ko = (size_t)ks * 32 * D_DIM;
        #pragma unroll
        for (int j = 0; j < 2; j++)
            gll16(bd0 + ko + (size_t)j * 16 * D_DIM, Bd + j * 4096 + ldsWaveByte);
    };
    auto aload = [&](uint4 (&as)[4], int ks) {
        #pragma unroll
        for (int m = 0; m < 4; m++) as[m] = *(const uint4*)(arow[m] + ks * 32);
    };
    const int ci = w * 16 + l16;
    auto consume = [&](int buf, uint4 (&as)[4]) {
        const float* Bd = ldsB + buf * 2048;
        bf16x8 bdf;
        #pragma unroll
        for (int i = 0; i < 8; i++) bdf[i] = (__bf16)Bd[(8 * g16 + i) * 64 + ci];
        #pragma unroll
        for (int m = 0; m < 4; m++) {
            acc[m] = __builtin_amdgcn_mfma_f32_16x16x32_bf16(
                __builtin_bit_cast(bf16x8, as[m]), bdf, acc[m], 0, 0, 0);
        }
    };

    stage(0, 0); aload(aS0, 0);
    stage(1, 1); aload(aS1, 1);

    const int NK = F_DIM / 32;  // 24
    for (int ks = 0; ks + 2 < NK; ks += 2) {
        asm volatile("s_waitcnt vmcnt(6)" ::: "memory");
        __builtin_amdgcn_s_barrier();
        __builtin_amdgcn_sched_barrier(0);
        consume(0, aS0);
        asm volatile("s_waitcnt lgkmcnt(0)" ::: "memory");
        __builtin_amdgcn_sched_barrier(0);
        __builtin_amdgcn_s_barrier();
        stage(0, ks + 2); aload(aS0, ks + 2);

        asm volatile("s_waitcnt vmcnt(6)" ::: "memory");
        __builtin_amdgcn_s_barrier();
        __builtin_amdgcn_sched_barrier(0);
        consume(1, aS1);
        asm volatile("s_waitcnt lgkmcnt(0)" ::: "memory");
        __builtin_amdgcn_sched_barrier(0);
        __builtin_amdgcn_s_barrier();
        stage(1, ks + 3); aload(aS1, ks + 3);
    }
    asm volatile("s_waitcnt vmcnt(6)" ::: "memory");
    __builtin_amdgcn_s_barrier();
    __builtin_amdgcn_sched_barrier(0);
    consume(0, aS0);
    asm volatile("s_waitcnt vmcnt(0)" ::: "memory");
    __builtin_amdgcn_s_barrier();
    __builtin_amdgcn_sched_barrier(0);
    consume(1, aS1);

    const int dcol = dtile * 64 + ci;
    #pragma unroll
    for (int m = 0; m < 4; m++) {
        #pragma unroll
        for (int r = 0; r < 4; r++) {
            const int p = mtile * 64 + m * 16 + g16 * 4 + r;
            if (p < n) {
                const int rid = ids[e * T_TOK + p];
                Y[(size_t)rid * D_DIM + dcol] = (__bf16)acc[m][r];
            }
        }
    }
}

// ---------------- combine: out[t] = sum_k w[t,k] * Y[t*8+k] ----------------
__global__ __launch_bounds__(256) void combine_kernel(
        const __bf16* __restrict__ Y, const float* __restrict__ pw,
        float* __restrict__ out) {
    const int t   = blockIdx.x;
    const int tid = threadIdx.x;
    const int d0  = tid * 8;
    float acc[8];
    #pragma unroll
    for (int j = 0; j < 8; j++) acc[j] = 0.f;
    #pragma unroll
    for (int k = 0; k < K_TOP; k++) {
        const float wgt = pw[t * K_TOP + k];
        bf16x8 v = *(const bf16x8*)(Y + (size_t)(t * K_TOP + k) * D_DIM + d0);
        #pragma unroll
        for (int j = 0; j < 8; j++) acc[j] += wgt * (float)v[j];
    }
    #pragma unroll
    for (int j = 0; j < 8; j++) out[(size_t)t * D_DIM + d0 + j] = acc[j];
}

extern "C" void kernel_launch(void* const* d_in, const int* in_sizes, int n_in,
                              void* d_out, int out_size, void* d_ws, size_t ws_size,
                              hipStream_t stream) {
    const float* x      = (const float*)d_in[0];
    const float* gw     = (const float*)d_in[1];
    const float* w_gate = (const float*)d_in[2];
    const float* w_up   = (const float*)d_in[3];
    const float* w_down = (const float*)d_in[4];
    float* out = (float*)d_out;

    char* ws = (char*)d_ws;
    int*    cnt = (int*)(ws);
    int*    ids = (int*)(ws + WS_IDS);
    float*  pw  = (float*)(ws + WS_PW);
    __bf16* xbf = (__bf16*)(ws + WS_XBF);
    __bf16* H   = (__bf16*)(ws + WS_H);
    __bf16* Y   = (__bf16*)(ws + WS_Y);

    zero_cnt_kernel<<<1, 64, 0, stream>>>(cnt);
    xcvt_kernel<<<T_TOK * D_DIM / (256 * 8), 256, 0, stream>>>(x, xbf);
    router_kernel<<<T_TOK, 256, 0, stream>>>(x, gw, pw, cnt, ids);
    // y-dim 8 covers any routing skew (n_e <= 512); empty tiles exit on cnt read.
    mlp1_kernel<<<dim3(F_DIM / 64, 8, E_NUM), 256, 0, stream>>>(xbf, w_gate, w_up, cnt, ids, H);
    mlp2_kernel<<<dim3(D_DIM / 64, 8, E_NUM), 256, 0, stream>>>(H, w_down, cnt, ids, Y);
    combine_kernel<<<T_TOK, 256, 0, stream>>>(Y, pw, out);
}